// Round 1
// baseline (291.737 us; speedup 1.0000x reference)
//
#include <hip/hip_runtime.h>
#include <cmath>

// ---------------- problem constants ----------------
#define M_ROWS   11520      // 2*5760
#define DIM      512
#define HID      1960
#define HIDP     2048       // padded HID (zeros)
#define OH       20
#define OW       36
#define LVEC     720        // OH*OW
#define NCH      40         // HID/49
#define BPRIME   16         // M_ROWS / LVEC
#define HP       66         // 60 + 2*3
#define WP       114        // 108 + 2*3

typedef unsigned short u16;
typedef __bf16 bf16x8 __attribute__((ext_vector_type(8)));
typedef float  f32x4  __attribute__((ext_vector_type(4)));

__device__ __forceinline__ u16 f2bf(float f) {
    unsigned u = __float_as_uint(f);
    u += 0x7fffu + ((u >> 16) & 1u);   // RNE
    return (u16)(u >> 16);
}
__device__ __forceinline__ float bf2f(u16 h) {
    return __uint_as_float(((unsigned)h) << 16);
}

__device__ __forceinline__ void gload_lds16(const void* g, void* l) {
    __builtin_amdgcn_global_load_lds(
        (const __attribute__((address_space(1))) void*)g,
        (__attribute__((address_space(3))) void*)l, 16, 0, 0);
}

// ---------------- fp32 -> bf16 converts ----------------
__global__ __launch_bounds__(256) void cvt_x(const float* __restrict__ src,
                                             u16* __restrict__ dst, int n) {
    int i = (blockIdx.x * 256 + threadIdx.x) * 4;
    if (i < n) {
        float4 v = *(const float4*)(src + i);
        ushort4 o;
        o.x = f2bf(v.x); o.y = f2bf(v.y); o.z = f2bf(v.z); o.w = f2bf(v.w);
        *(ushort4*)(dst + i) = o;
    }
}

// W1: (1960,512) -> (2048,512), pad rows with zero
__global__ __launch_bounds__(256) void cvt_w1(const float* __restrict__ src,
                                              u16* __restrict__ dst) {
    int i = (blockIdx.x * 256 + threadIdx.x) * 4;   // over 2048*512
    ushort4 o;
    if (i < HID * DIM) {
        float4 v = *(const float4*)(src + i);
        o.x = f2bf(v.x); o.y = f2bf(v.y); o.z = f2bf(v.z); o.w = f2bf(v.w);
    } else {
        o.x = o.y = o.z = o.w = 0;
    }
    *(ushort4*)(dst + i) = o;
}

// W2: (512,1960) -> (512,2048), pad cols with zero. 1960 % 4 == 0.
__global__ __launch_bounds__(256) void cvt_w2(const float* __restrict__ src,
                                              u16* __restrict__ dst) {
    int i = (blockIdx.x * 256 + threadIdx.x) * 4;   // over 512*2048
    int d = i / HIDP, c = i % HIDP;
    ushort4 o;
    if (c < HID) {
        float4 v = *(const float4*)(src + d * HID + c);
        o.x = f2bf(v.x); o.y = f2bf(v.y); o.z = f2bf(v.z); o.w = f2bf(v.w);
    } else {
        o.x = o.y = o.z = o.w = 0;
    }
    *(ushort4*)(dst + i) = o;
}

// ---------------- bf16 NT-GEMM: C[m,n] = sum_k A[m,k]*B[n,k] + bias[n] ----------------
// 128x128 tile, BK=64, 4 waves (2x2), each wave 64x64 via 4x4 mfma_f32_16x16x32_bf16.
// LDS staged with global_load_lds width 16; XOR swizzle applied on the GLOBAL side
// (LDS dest is wave-uniform+lane*16) so ds_read_b128 is bank-conflict-free.
template <int OUT_BF16>
__global__ __launch_bounds__(256) void gemm_bt(const u16* __restrict__ A,
                                               const u16* __restrict__ B,
                                               const float* __restrict__ bias,
                                               int biasN, void* __restrict__ Cout,
                                               int N, int K) {
    __shared__ u16 sA[128 * 64];
    __shared__ u16 sB[128 * 64];

    const int tid  = threadIdx.x;
    const int ntn  = N >> 7;
    const int bm   = blockIdx.x / ntn;
    const int bn   = blockIdx.x % ntn;
    const int lane = tid & 63;
    const int wv   = tid >> 6;
    const int wm   = (wv >> 1) * 64;
    const int wn   = (wv & 1) * 64;
    const int r    = lane & 15;
    const int quad = lane >> 4;

    const size_t Arow0 = (size_t)bm * 128 * K;
    const size_t Brow0 = (size_t)bn * 128 * K;

    f32x4 acc[4][4] = {};

    for (int kt = 0; kt < K; kt += 64) {
        __syncthreads();
#pragma unroll
        for (int i = 0; i < 4; i++) {
            int e   = i * 256 + tid;       // 16B chunk id within tile
            int row = e >> 3;              // 8 chunks per 128B row
            int cp  = e & 7;
            int cg  = cp ^ (row & 7);      // global chunk fetched into LDS slot cp
            gload_lds16(A + Arow0 + (size_t)row * K + kt + cg * 8, (char*)sA + e * 16);
            gload_lds16(B + Brow0 + (size_t)row * K + kt + cg * 8, (char*)sB + e * 16);
        }
        __syncthreads();
#pragma unroll
        for (int kk = 0; kk < 2; kk++) {
            bf16x8 af[4], bg[4];
#pragma unroll
            for (int t = 0; t < 4; t++) {
                int row = wm + t * 16 + r;
                int c   = (kk * 4 + quad) ^ (row & 7);
                af[t] = *(const bf16x8*)(sA + row * 64 + c * 8);
            }
#pragma unroll
            for (int u = 0; u < 4; u++) {
                int row = wn + u * 16 + r;
                int c   = (kk * 4 + quad) ^ (row & 7);
                bg[u] = *(const bf16x8*)(sB + row * 64 + c * 8);
            }
#pragma unroll
            for (int t = 0; t < 4; t++)
#pragma unroll
                for (int u = 0; u < 4; u++)
                    acc[t][u] = __builtin_amdgcn_mfma_f32_16x16x32_bf16(
                        af[t], bg[u], acc[t][u], 0, 0, 0);
        }
    }

    // epilogue: C/D layout col = lane&15 (n), row = quad*4+q (m)
    const int gm0 = bm * 128 + wm;
    const int gn0 = bn * 128 + wn;
#pragma unroll
    for (int u = 0; u < 4; u++) {
        int gn = gn0 + u * 16 + r;
        float bv = (gn < biasN) ? bias[gn] : 0.0f;
#pragma unroll
        for (int t = 0; t < 4; t++) {
            int gm = gm0 + t * 16 + quad * 4;
#pragma unroll
            for (int q = 0; q < 4; q++) {
                float v = acc[t][u][q] + bv;
                if (OUT_BF16)
                    ((u16*)Cout)[(size_t)(gm + q) * N + gn] = f2bf(v);
                else
                    ((float*)Cout)[(size_t)(gm + q) * N + gn] = v;
            }
        }
    }
}

// ---------------- fold -> /norm -> crop+repad -> unfold -> gelu, in place ----------------
// One block per (b', ch): reads h slice (49 x 720) scattered from global, builds the
// normalized padded image in LDS (borders = 0 due to crop+repad), then writes
// g = gelu(img[ky+3oy, kx+3ox]) back over the same global region. Read/write sets
// are identical and block-local, so in-place is race-free.
__global__ __launch_bounds__(256) void mid_fold_unfold(u16* __restrict__ hg) {
    __shared__ float f[HP * WP];   // 66*114*4 = 30096 B

    const int bp = blockIdx.x / NCH;
    const int ch = blockIdx.x % NCH;
    const int n0 = bp * LVEC;
    const int c0 = ch * 49;
    const int tid = threadIdx.x;

    for (int p = tid; p < HP * WP; p += 256) {
        int py = p / WP, px = p % WP;
        float val = 0.0f;
        if (py >= 3 && py <= 62 && px >= 3 && px <= 110) {
            int kys[3], kxs[3], nky = 0, nkx = 0;
            for (int ky = py % 3; ky < 7; ky += 3) {
                int oy = (py - ky) / 3;
                if (py - ky >= 0 && oy < OH) kys[nky++] = ky;
            }
            for (int kx = px % 3; kx < 7; kx += 3) {
                int ox = (px - kx) / 3;
                if (px - kx >= 0 && ox < OW) kxs[nkx++] = kx;
            }
            float sum = 0.0f;
            for (int a = 0; a < nky; a++) {
                int ky = kys[a], oy = (py - ky) / 3;
                for (int b = 0; b < nkx; b++) {
                    int kx = kxs[b], ox = (px - kx) / 3;
                    sum += bf2f(hg[(size_t)(n0 + oy * OW + ox) * HIDP + c0 + ky * 7 + kx]);
                }
            }
            val = sum / (float)(nky * nkx);
        }
        f[p] = val;
    }
    __syncthreads();

    for (int i = tid; i < 49 * LVEC; i += 256) {
        int k = i % 49, l = i / 49;
        int ky = k / 7, kx = k % 7;
        int oy = l / OW, ox = l % OW;
        float v = f[(ky + 3 * oy) * WP + (kx + 3 * ox)];
        float g = 0.5f * v * (1.0f + erff(v * 0.70710678118654752f));  // exact gelu
        hg[(size_t)(n0 + l) * HIDP + c0 + k] = f2bf(g);
    }
}

// ---------------- launch ----------------
extern "C" void kernel_launch(void* const* d_in, const int* in_sizes, int n_in,
                              void* d_out, int out_size, void* d_ws, size_t ws_size,
                              hipStream_t stream) {
    (void)in_sizes; (void)n_in; (void)out_size; (void)ws_size;
    const float* x  = (const float*)d_in[0];
    const float* W1 = (const float*)d_in[1];
    const float* b1 = (const float*)d_in[2];
    const float* W2 = (const float*)d_in[3];
    const float* b2 = (const float*)d_in[4];
    float* out = (float*)d_out;

    char* ws = (char*)d_ws;
    u16* xb  = (u16*)(ws);                                   // 11520*512*2  = 11,796,480
    u16* W1b = (u16*)(ws + 11796480);                        // 2048*512*2   =  2,097,152
    u16* W2b = (u16*)(ws + 11796480 + 2097152);              // 512*2048*2   =  2,097,152
    u16* hg  = (u16*)(ws + 11796480 + 2097152 + 2097152);    // 11520*2048*2 = 47,185,920

    // converts
    cvt_x <<<(M_ROWS * DIM) / (256 * 4), 256, 0, stream>>>(x, xb, M_ROWS * DIM);
    cvt_w1<<<(HIDP * DIM) / (256 * 4), 256, 0, stream>>>(W1, W1b);
    cvt_w2<<<(DIM * HIDP) / (256 * 4), 256, 0, stream>>>(W2, W2b);

    // GEMM1: h = x @ W1^T + b1  -> bf16 (11520 x 2048, cols >=1960 are zero)
    gemm_bt<1><<<(M_ROWS / 128) * (HIDP / 128), 256, 0, stream>>>(
        xb, W1b, b1, HID, (void*)hg, HIDP, DIM);

    // middle: fold / norm / unfold / gelu, in place on hg
    mid_fold_unfold<<<BPRIME * NCH, 256, 0, stream>>>(hg);

    // GEMM2: out = g @ W2^T + b2 -> fp32 (11520 x 512)
    gemm_bt<0><<<(M_ROWS / 128) * (DIM / 128), 256, 0, stream>>>(
        hg, W2b, b2, DIM, (void*)out, DIM, HIDP);
}